// Round 1
// baseline (234.244 us; speedup 1.0000x reference)
//
#include <hip/hip_runtime.h>
#include <cstdint>

#define NPRED 25200      // total predictions (8400 positions * 3 anchors)
#define NPOS  8400
#define NCLS  80
#define CAP   1024       // max boxes per class (mean ~315, 40 sigma headroom)

__device__ __forceinline__ float sigmoidf_(float x) { return 1.0f / (1.0f + expf(-x)); }

__global__ void zero_counts_kernel(int* counts) {
    if (threadIdx.x < NCLS) counts[threadIdx.x] = 0;
}

// One thread per (anchor, position). Thread mapping a = t/8400, pos = t%8400 so
// a wave reads 64 consecutive positions of the same channel plane (coalesced).
__global__ __launch_bounds__(256) void decode_kernel(
    const float* __restrict__ ps, const float* __restrict__ pm, const float* __restrict__ pl,
    float* __restrict__ out, int* __restrict__ counts, float* __restrict__ classbuf)
{
    int t = blockIdx.x * blockDim.x + threadIdx.x;
    if (t >= NPRED) return;
    int a   = t / NPOS;
    int pos = t - a * NPOS;

    const float* p; int HW, W, base, si; float stride;
    if (pos < 6400)      { p = ps; HW = 6400; W = 80; stride = 8.f;  base = 0;    si = 0; }
    else if (pos < 8000) { p = pm; HW = 1600; W = 40; stride = 16.f; base = 6400; si = 1; }
    else                 { p = pl; HW = 400;  W = 20; stride = 32.f; base = 8000; si = 2; }
    int local = pos - base;
    int y = local / W;
    int x = local - y * W;

    const float AW[9] = {10.f,16.f,33.f, 30.f,62.f,59.f, 116.f,156.f,373.f};
    const float AH[9] = {13.f,30.f,23.f, 61.f,45.f,119.f, 90.f,198.f,326.f};
    float aw = AW[si*3 + a], ah = AH[si*3 + a];

    // ---- class softmax * obj, argmax replicated like the reference ----
    const float* cb = p + (size_t)(3 + a * NCLS) * HW + local;
    float l[NCLS];
    float m = -INFINITY;
#pragma unroll
    for (int c = 0; c < NCLS; c++) { l[c] = cb[(size_t)c * HW]; m = fmaxf(m, l[c]); }
    float s = 0.f;
#pragma unroll
    for (int c = 0; c < NCLS; c++) { float e = expf(l[c] - m); l[c] = e; s += e; }
    float obj = sigmoidf_(p[(size_t)a * HW + local]);
    float best = -1.f; int bi = 0;
#pragma unroll
    for (int c = 0; c < NCLS; c++) {
        float sc = l[c] / s * obj;           // same op order as softmax*obj in ref
        if (sc > best) { best = sc; bi = c; } // strict > keeps first max (jnp.argmax)
    }

    // ---- box decode ----
    const float* rb = p + (size_t)(3 + 3 * NCLS + a * 4) * HW + local;
    float tx = rb[0], ty = rb[(size_t)HW], tw = rb[(size_t)2 * HW], th = rb[(size_t)3 * HW];
    float cx = (sigmoidf_(tx) + (float)x) * stride;
    float cy = (sigmoidf_(ty) + (float)y) * stride;
    float bw = expf(tw) * aw;
    float bh = expf(th) * ah;
    float x1 = fminf(fmaxf((cx - bw / 2.f) / 640.f, 0.f), 1.f);
    float y1 = fminf(fmaxf((cy - bh / 2.f) / 640.f, 0.f), 1.f);
    float x2 = fminf(fmaxf((cx + bw / 2.f) / 640.f, 0.f), 1.f);
    float y2 = fminf(fmaxf((cy + bh / 2.f) / 640.f, 0.f), 1.f);

    int g = pos * 3 + a;                      // reference global ordering
    float clsf = (float)bi;
    float* o = out + (size_t)g * 7;
    o[0] = x1; o[1] = y1; o[2] = x2; o[3] = y2;
    o[4] = best; o[5] = clsf; o[6] = 0.f;     // keep filled by NMS kernel

    if (best >= 0.001f) {                     // invalid boxes never keep nor suppress
        int slot = atomicAdd(&counts[bi], 1);
        if (slot < CAP) {
            float off = clsf * 2.0f;          // replicate offset rounding (ref IoU uses it)
            float* r = classbuf + (size_t)(bi * CAP + slot) * 6;
            r[0] = x1 + off; r[1] = y1 + off; r[2] = x2 + off; r[3] = y2 + off;
            r[4] = best; r[5] = __int_as_float(g);
        }
    }
}

// One block per class. Bitonic sort (score desc, g asc) then greedy NMS in LDS.
__global__ __launch_bounds__(256) void nms_kernel(
    const int* __restrict__ counts, const float* __restrict__ classbuf, float* __restrict__ out)
{
    int c = blockIdx.x;
    int n = counts[c]; if (n > CAP) n = CAP;
    int tid = threadIdx.x;

    __shared__ unsigned long long key[CAP];
    __shared__ float bx1[CAP], by1[CAP], bx2[CAP], by2[CAP], barea[CAP];
    __shared__ int   bg[CAP];
    __shared__ unsigned char supp[CAP];

    const float* cls = classbuf + (size_t)c * CAP * 6;

    for (int i = tid; i < CAP; i += 256) {
        if (i < n) {
            float sc = cls[i * 6 + 4];
            unsigned int u = __float_as_uint(sc);
            u = (u & 0x80000000u) ? ~u : (u | 0x80000000u);  // orderable ascending
            unsigned int inv = ~u;                            // ascending inv = score desc
            int g = __float_as_int(cls[i * 6 + 5]);
            key[i] = ((unsigned long long)inv << 25)
                   | ((unsigned long long)(unsigned)g << 10)
                   | (unsigned long long)i;
        } else {
            key[i] = ~0ULL;
        }
    }
    __syncthreads();

    // bitonic sort ascending over CAP elements
    for (int k = 2; k <= CAP; k <<= 1) {
        for (int j = k >> 1; j > 0; j >>= 1) {
            for (int t = tid; t < CAP; t += 256) {
                int ixj = t ^ j;
                if (ixj > t) {
                    unsigned long long a0 = key[t], b0 = key[ixj];
                    bool up = (t & k) == 0;
                    if ((a0 > b0) == up) { key[t] = b0; key[ixj] = a0; }
                }
            }
            __syncthreads();
        }
    }

    // gather sorted boxes
    for (int i = tid; i < CAP; i += 256) {
        supp[i] = 0;
        if (i < n) {
            int slot = (int)(key[i] & 1023ULL);
            float X1 = cls[slot * 6 + 0], Y1 = cls[slot * 6 + 1];
            float X2 = cls[slot * 6 + 2], Y2 = cls[slot * 6 + 3];
            bx1[i] = X1; by1[i] = Y1; bx2[i] = X2; by2[i] = Y2;
            barea[i] = (X2 - X1) * (Y2 - Y1);   // same formula/inputs as ref areas
            bg[i] = (int)((key[i] >> 10) & 0x7FFFULL);
        }
    }
    __syncthreads();

    // greedy scan: iteration i suppresses later boxes; supp[i] visible via prior barrier
    for (int i = 0; i < n; i++) {
        if (!supp[i]) {
            float X1 = bx1[i], Y1 = by1[i], X2 = bx2[i], Y2 = by2[i], A = barea[i];
            for (int j = i + 1 + tid; j < n; j += 256) {
                float xx1 = fmaxf(X1, bx1[j]);
                float yy1 = fmaxf(Y1, by1[j]);
                float xx2 = fminf(X2, bx2[j]);
                float yy2 = fminf(Y2, by2[j]);
                float w = fmaxf(1e-28f, xx2 - xx1);
                float h = fmaxf(1e-28f, yy2 - yy1);
                float inter = w * h;
                float iou = inter / ((A + barea[j]) - inter);  // ref op order
                if (iou > 0.6f) supp[j] = 1;
            }
        }
        __syncthreads();
    }

    for (int i = tid; i < n; i += 256)
        if (!supp[i]) out[(size_t)bg[i] * 7 + 6] = 1.0f;
}

extern "C" void kernel_launch(void* const* d_in, const int* in_sizes, int n_in,
                              void* d_out, int out_size, void* d_ws, size_t ws_size,
                              hipStream_t stream) {
    const float* ps = (const float*)d_in[0];
    const float* pm = (const float*)d_in[1];
    const float* pl = (const float*)d_in[2];
    float* out = (float*)d_out;

    int*   counts   = (int*)d_ws;
    float* classbuf = (float*)((char*)d_ws + 1024);   // 80*1024*6 floats ~ 1.97 MB

    zero_counts_kernel<<<1, 128, 0, stream>>>(counts);
    decode_kernel<<<(NPRED + 255) / 256, 256, 0, stream>>>(ps, pm, pl, out, counts, classbuf);
    nms_kernel<<<NCLS, 256, 0, stream>>>(counts, classbuf, out);
}